// Round 15
// baseline (208.054 us; speedup 1.0000x reference)
//
#include <hip/hip_runtime.h>

#define B_ 16
#define NC 1024
#define NF 4096
#define CIN 256
#define CSKIP 128
#define CHID 256
#define MTOT (B_ * NF)   // 65536
#define EPS_ 1e-16f

typedef _Float16 f16;
typedef __attribute__((ext_vector_type(8))) _Float16 f16x8;
typedef __attribute__((ext_vector_type(4))) _Float16 f16x4;
typedef __attribute__((ext_vector_type(4))) float f32x4;

// K-permutation: stored j holds logical k(j) = (j&~63) + (j&3)*16 + ((j>>2)&15).
// y and the LDS h1 tile live in this permuted column space; W2T rows and b1p
// are permuted to match, so the layer-2 GEMM cancels the permutation exactly.

// ---------------- async global->LDS, 16B per lane, linear dest ----------------
__device__ __forceinline__ void gload16(const void* g, void* l)
{
    __builtin_amdgcn_global_load_lds(
        (const __attribute__((address_space(1))) unsigned int*)g,
        (__attribute__((address_space(3))) unsigned int*)l, 16, 0, 0);
}

// ---------------- misc2: gemm_y (0..255) + wconv (256..640) + tail (641..1664) ----------------
__global__ __launch_bounds__(256, 4) void misc_kernel(
    const float* __restrict__ x,
    const float* __restrict__ pos_skip, const int* __restrict__ batch_skip,
    const float* __restrict__ W1, const float* __restrict__ W2,
    const float* __restrict__ b1,
    f16* __restrict__ W1bT, f16* __restrict__ W2T, float* __restrict__ b1p,
    f16* __restrict__ y, float* __restrict__ out_tail)
{
    __shared__ __align__(16) char smem[32768];
    const int bid = blockIdx.x;

    if (bid < 256) {
        // ---- y = x @ W1a^T (M=16384, K=256), K-permuted f16 store ----
        f16* As = (f16*)smem;              // [128][64]
        f16* Bs = (f16*)(smem + 16384);    // [128][64]
        const int m0 = (bid >> 1) * 128;
        const int n0 = (bid & 1) * 128;
        const int tid  = threadIdx.x;
        const int lane = tid & 63;
        const int wid  = tid >> 6;
        const int wr   = wid >> 1, wc = wid & 1;
        const int srow = tid >> 1;
        const int scg  = tid & 1;
        const int bn4  = (tid & 31) << 2;
        const int bkb  = (tid >> 5) << 3;

        f32x4 acc[4][4] = {};
        for (int k0 = 0; k0 < 256; k0 += 64) {
            {   // A: x rows -> f16, swizzled ds_write
                const float* p = x + (size_t)(m0 + srow) * 256 + k0 + scg * 32;
                float v[32];
#pragma unroll
                for (int j = 0; j < 8; ++j) {
                    float4 a = ((const float4*)p)[j];
                    v[j*4+0]=a.x; v[j*4+1]=a.y; v[j*4+2]=a.z; v[j*4+3]=a.w;
                }
#pragma unroll
                for (int j = 0; j < 4; ++j) {
                    f16x8 hh;
#pragma unroll
                    for (int t2 = 0; t2 < 8; ++t2) hh[t2] = (f16)v[j*8+t2];
                    const int sphys = (scg*4 + j) ^ (srow & 7);
                    *(f16x8*)((char*)As + srow*128 + sphys*16) = hh;
                }
            }
            // B: W1 4x4 transpose-convert -> Bs[n][k], swizzled
#pragma unroll
            for (int c = 0; c < 2; ++c) {
                const int k = bkb + c * 4;
                const float* wp = W1 + (size_t)(k0 + k) * 256 + n0 + bn4;
                float4 r0 = *(const float4*)(wp);
                float4 r1 = *(const float4*)(wp + 256);
                float4 r2 = *(const float4*)(wp + 512);
                float4 r3 = *(const float4*)(wp + 768);
                const int half  = (k >> 2) & 1;
                const int kslot = k >> 3;
                f16x4 t0, t1, t2v, t3;
                t0[0]=(f16)r0.x; t0[1]=(f16)r1.x; t0[2]=(f16)r2.x; t0[3]=(f16)r3.x;
                t1[0]=(f16)r0.y; t1[1]=(f16)r1.y; t1[2]=(f16)r2.y; t1[3]=(f16)r3.y;
                t2v[0]=(f16)r0.z; t2v[1]=(f16)r1.z; t2v[2]=(f16)r2.z; t2v[3]=(f16)r3.z;
                t3[0]=(f16)r0.w; t3[1]=(f16)r1.w; t3[2]=(f16)r2.w; t3[3]=(f16)r3.w;
                *(f16x4*)((char*)Bs + (bn4+0)*128 + ((kslot ^ ((bn4+0)&7))*16) + half*8) = t0;
                *(f16x4*)((char*)Bs + (bn4+1)*128 + ((kslot ^ ((bn4+1)&7))*16) + half*8) = t1;
                *(f16x4*)((char*)Bs + (bn4+2)*128 + ((kslot ^ ((bn4+2)&7))*16) + half*8) = t2v;
                *(f16x4*)((char*)Bs + (bn4+3)*128 + ((kslot ^ ((bn4+3)&7))*16) + half*8) = t3;
            }
            __syncthreads();
#pragma unroll
            for (int h = 0; h < 2; ++h) {
                f16x8 aF[4], bF[4];
#pragma unroll
                for (int m = 0; m < 4; ++m) {
                    const int row  = wr*64 + m*16 + (lane & 15);
                    const int kg   = (h<<2) + (lane>>4);
                    const int slot = kg ^ (row & 7);
                    aF[m] = *(const f16x8*)((const char*)As + row*128 + slot*16);
                }
#pragma unroll
                for (int n = 0; n < 4; ++n) {
                    const int row  = wc*64 + n*16 + (lane & 15);
                    const int kg   = (h<<2) + (lane>>4);
                    const int slot = kg ^ (row & 7);
                    bF[n] = *(const f16x8*)((const char*)Bs + row*128 + slot*16);
                }
#pragma unroll
                for (int m = 0; m < 4; ++m)
#pragma unroll
                    for (int n = 0; n < 4; ++n)
                        acc[m][n] = __builtin_amdgcn_mfma_f32_16x16x32_f16(
                            aF[m], bF[n], acc[m][n], 0, 0, 0);
            }
            __syncthreads();
        }
        const int qq = lane & 15;
#pragma unroll
        for (int m = 0; m < 4; ++m) {
            const int rb = wr*64 + m*16 + ((lane>>4) << 2);
#pragma unroll
            for (int r = 0; r < 4; ++r) {
                const int rg = m0 + rb + r;
                f16x4 hv;
#pragma unroll
                for (int n = 0; n < 4; ++n) hv[n] = (f16)acc[m][n][r];
                *(f16x4*)&y[(size_t)rg * 256 + n0 + wc*64 + qq*4] = hv;
            }
        }
    } else if (bid < 641) {
        // ---- wconv: W1bT [256][128], W2T [256][256] (K-perm rows), b1p ----
        const int t = (bid - 256) * 256 + threadIdx.x;
        if (t < 128 * 256) {
            const int k = t >> 8, n = t & 255;
            W1bT[n * 128 + k] = (f16)W1[(256 + k) * 256 + n];
        } else if (t < 128 * 256 + 256 * 256) {
            const int u = t - 128 * 256;
            const int n = u >> 8, j = u & 255;
            const int k = (j & ~63) + ((j & 3) << 4) + ((j >> 2) & 15);
            W2T[n * 256 + j] = (f16)W2[k * 256 + n];
        } else if (t < 128 * 256 + 256 * 256 + 256) {
            const int j = t - (128 * 256 + 256 * 256);
            const int k = (j & ~63) + ((j & 3) << 4) + ((j >> 2) & 15);
            b1p[j] = b1[k];
        }
    } else {
        // ---- tail: pos_skip passthrough + batch_skip as float ----
        const int i = (bid - 641) * 256 + threadIdx.x;
        const int npos = MTOT * 3;
        if (i < npos)               out_tail[i] = pos_skip[i];
        else if (i < npos + MTOT)   out_tail[i] = (float)batch_skip[i - npos];
    }
}

// ---------------- fused: in-block kNN + layer1b + gather + layer2 ----------------
// BM=64, BN=256, 1024 blocks, LDS 67072 B -> 2 blocks/CU.
// Phase0 kNN (VALU) overlaps the co-resident block's staging/MFMA (m114).
// LDS: [0,32K) Bs | [32K,64K) region R (phase0: cpos 16K; loop1: As 8K;
// after mid-epilogue: h1s 32K) | [64K, +1.5K) knn results (idx,w per row).
__global__ __launch_bounds__(256, 2) void fused_all(
    const float* __restrict__ pos, const float* __restrict__ pos_skip,
    const float* __restrict__ A,      // x_skip [M][128]
    const f16* __restrict__ B1t,      // W1bT [256][128]
    const f16* __restrict__ y,        // [16384][256], permuted cols
    const float* __restrict__ b1p,    // permuted
    const f16* __restrict__ B2t,      // W2T [256][256]
    const float* __restrict__ b2,
    float* __restrict__ out)
{
    __shared__ __align__(16) char lds[67072];
    f16*   Bs  = (f16*)lds;            // [256][64], both loops
    f16*   As  = (f16*)(lds + 32768);  // [64][64], loop1 only
    char*  h1s = lds + 32768;          // [64][256] f16, from mid-epilogue on
    int*   kni = (int*)(lds + 65536);          // [64][3]
    float* knw = (float*)(lds + 65536 + 768);  // [64][3]

    const int tid  = threadIdx.x;
    const int lane = tid & 63;
    const int wid  = tid >> 6;
    const int wr   = wid >> 1, wc = wid & 1;
    const int m0   = blockIdx.x * 64;
    const int bat  = m0 >> 12;          // batch (4096 rows each)

    // ---- phase 0: kNN for rows m0..m0+63 (4 thr/row x 256 candidates) ----
    {
        float4* cpos = (float4*)(lds + 32768);   // 16 KB
        const float* cp = pos + (size_t)(bat << 10) * 3;
        for (int i = tid; i < NC; i += 256)
            cpos[i] = make_float4(cp[i*3], cp[i*3+1], cp[i*3+2], 0.0f);
        __syncthreads();

        const int fl = tid >> 2;         // fine row 0..63
        const int q  = tid & 3;          // quarter
        const int f  = m0 + fl;
        const float px = pos_skip[f*3+0];
        const float py = pos_skip[f*3+1];
        const float pz = pos_skip[f*3+2];

        float d0 = 3.4e38f, d1 = 3.4e38f, d2 = 3.4e38f;
        int   i0 = 0, i1 = 0, i2 = 0;
        const int jb = q << 8;
#pragma unroll 4
        for (int jj = 0; jj < 256; ++jj) {
            const int j = jb + jj;
            float4 c = cpos[j];
            float dx = px - c.x, dy = py - c.y, dz = pz - c.z;
            float d = fmaf(dx, dx, fmaf(dy, dy, dz * dz));
            const bool c2 = d < d2, c1 = d < d1, c0 = d < d0;
            d2 = c1 ? d1 : (c2 ? d : d2);  i2 = c1 ? i1 : (c2 ? j : i2);
            d1 = c0 ? d0 : (c1 ? d : d1);  i1 = c0 ? i0 : (c1 ? j : i1);
            d0 = c0 ? d  : d0;             i0 = c0 ? j  : i0;
        }
        // merge quarters in-register: xor1 then xor2. Only q==0's result is
        // used; its insert order is ascending-index -> top_k tie rule holds.
#pragma unroll
        for (int st = 1; st <= 2; st <<= 1) {
            float e0 = __shfl_xor(d0, st, 64), e1 = __shfl_xor(d1, st, 64), e2 = __shfl_xor(d2, st, 64);
            int   g0 = __shfl_xor(i0, st, 64), g1 = __shfl_xor(i1, st, 64), g2 = __shfl_xor(i2, st, 64);
#pragma unroll
            for (int s = 0; s < 3; ++s) {
                const float d = s == 0 ? e0 : (s == 1 ? e1 : e2);
                const int   j = s == 0 ? g0 : (s == 1 ? g1 : g2);
                const bool c2 = d < d2, c1 = d < d1, c0 = d < d0;
                d2 = c1 ? d1 : (c2 ? d : d2);  i2 = c1 ? i1 : (c2 ? j : i2);
                d1 = c0 ? d0 : (c1 ? d : d1);  i1 = c0 ? i0 : (c1 ? j : i1);
                d0 = c0 ? d  : d0;             i0 = c0 ? j  : i0;
            }
        }
        if (q == 0) {
            const float w0 = 1.0f / fmaxf(d0, EPS_);
            const float w1 = 1.0f / fmaxf(d1, EPS_);
            const float w2 = 1.0f / fmaxf(d2, EPS_);
            const float inv = 1.0f / (w0 + w1 + w2);
            kni[fl*3+0] = i0; kni[fl*3+1] = i1; kni[fl*3+2] = i2;
            knw[fl*3+0] = w0 * inv; knw[fl*3+1] = w1 * inv; knw[fl*3+2] = w2 * inv;
        }
        __syncthreads();   // cpos dead; knn results visible; As may now be written
    }

    const int srow_l = lane >> 3;
    const int kch    = (lane & 7) ^ ((lane >> 3) & 7);

    // ---- loop1: acc = x_skip @ W1bT^T  (K=128) ----
    f32x4 acc[2][8] = {};
    for (int k0 = 0; k0 < 128; k0 += 64) {
#pragma unroll
        for (int r = 0; r < 8; ++r) {
            const int c = (wid << 3) + r;
            const int row = (c << 3) + srow_l;
            gload16(B1t + (size_t)row * 128 + k0 + kch * 8, (char*)Bs + (c << 10));
        }
        {   // A: 4 thr/row, 16 ch each -> f16 swizzled
            const int arow = tid >> 2, acg = tid & 3;
            const float* p = A + (size_t)(m0 + arow) * 128 + k0 + acg * 16;
            float v[16];
#pragma unroll
            for (int j = 0; j < 4; ++j) {
                float4 a = ((const float4*)p)[j];
                v[j*4+0]=a.x; v[j*4+1]=a.y; v[j*4+2]=a.z; v[j*4+3]=a.w;
            }
#pragma unroll
            for (int j = 0; j < 2; ++j) {
                f16x8 hh;
#pragma unroll
                for (int t2 = 0; t2 < 8; ++t2) hh[t2] = (f16)v[j*8+t2];
                const int sphys = (acg*2 + j) ^ (arow & 7);
                *(f16x8*)((char*)As + arow*128 + sphys*16) = hh;
            }
        }
        __syncthreads();
#pragma unroll
        for (int h = 0; h < 2; ++h) {
            f16x8 aF[2];
#pragma unroll
            for (int m = 0; m < 2; ++m) {
                const int row  = wr*32 + m*16 + (lane & 15);
                const int kg   = (h<<2) + (lane>>4);
                const int slot = kg ^ (row & 7);
                aF[m] = *(const f16x8*)((const char*)As + row*128 + slot*16);
            }
#pragma unroll
            for (int n = 0; n < 8; ++n) {
                const int row  = wc*128 + n*16 + (lane & 15);
                const int kg   = (h<<2) + (lane>>4);
                const int slot = kg ^ (row & 7);
                f16x8 bF = *(const f16x8*)((const char*)Bs + row*128 + slot*16);
#pragma unroll
                for (int m = 0; m < 2; ++m)
                    acc[m][n] = __builtin_amdgcn_mfma_f32_16x16x32_f16(
                        aF[m], bF, acc[m][n], 0, 0, 0);
            }
        }
        __syncthreads();
    }

    // ---- mid-epilogue: h1s = relu(acc + sum w_j*y[g_j] + b1p), swizzled LDS ----
    const int qq  = lane & 15;
    const int gb  = bat << 10;          // batch base into y rows
    const f32x4 bv0 = *(const f32x4*)&b1p[wc*128 + qq*4];
    const f32x4 bv1 = *(const f32x4*)&b1p[wc*128 + 64 + qq*4];
#pragma unroll
    for (int m = 0; m < 2; ++m) {
        const int rb = wr*32 + m*16 + ((lane>>4) << 2);
#pragma unroll
        for (int r = 0; r < 4; ++r) {
            const int rl = rb + r;               // local row 0..63
            const int i0 = gb + kni[rl*3+0];
            const int i1 = gb + kni[rl*3+1];
            const int i2 = gb + kni[rl*3+2];
            const float w0 = knw[rl*3+0], w1 = knw[rl*3+1], w2 = knw[rl*3+2];
#pragma unroll
            for (int g = 0; g < 2; ++g) {
                const int jb2 = wc*128 + g*64 + qq*4;
                f16x4 y0 = *(const f16x4*)&y[(size_t)i0 * 256 + jb2];
                f16x4 y1 = *(const f16x4*)&y[(size_t)i1 * 256 + jb2];
                f16x4 y2 = *(const f16x4*)&y[(size_t)i2 * 256 + jb2];
                const f32x4 bv = g ? bv1 : bv0;
                f16x4 hv;
#pragma unroll
                for (int n = 0; n < 4; ++n) {
                    float v = acc[m][g*4+n][r]
                            + w0*(float)y0[n] + w1*(float)y1[n] + w2*(float)y2[n]
                            + bv[n];
                    hv[n] = (f16)fmaxf(v, 0.0f);
                }
                const int slot = jb2 >> 3;
                const int phys = (slot & ~7) | ((slot & 7) ^ (rl & 7));
                *(f16x4*)(h1s + rl*512 + phys*16 + ((jb2 >> 2) & 1) * 8) = hv;
            }
        }
    }
    __syncthreads();

    // ---- loop2: acc2 = h1s @ W2T^T  (K=256, A from LDS) ----
    f32x4 acc2[2][8] = {};
    for (int k0 = 0; k0 < 256; k0 += 64) {
#pragma unroll
        for (int r = 0; r < 8; ++r) {
            const int c = (wid << 3) + r;
            const int row = (c << 3) + srow_l;
            gload16(B2t + (size_t)row * 256 + k0 + kch * 8, (char*)Bs + (c << 10));
        }
        __syncthreads();
#pragma unroll
        for (int h = 0; h < 2; ++h) {
            f16x8 aF[2];
#pragma unroll
            for (int m = 0; m < 2; ++m) {
                const int row   = wr*32 + m*16 + (lane & 15);
                const int kg    = (h<<2) + (lane>>4);
                const int aslot = (k0 >> 3) + (kg ^ (row & 7));
                aF[m] = *(const f16x8*)(h1s + row*512 + aslot*16);
            }
#pragma unroll
            for (int n = 0; n < 8; ++n) {
                const int row  = wc*128 + n*16 + (lane & 15);
                const int kg   = (h<<2) + (lane>>4);
                const int slot = kg ^ (row & 7);
                f16x8 bF = *(const f16x8*)((const char*)Bs + row*128 + slot*16);
#pragma unroll
                for (int m = 0; m < 2; ++m)
                    acc2[m][n] = __builtin_amdgcn_mfma_f32_16x16x32_f16(
                        aF[m], bF, acc2[m][n], 0, 0, 0);
            }
        }
        __syncthreads();
    }

    // ---- final epilogue: out = relu(acc2 + b2), f32 standard layout ----
#pragma unroll
    for (int m = 0; m < 2; ++m) {
#pragma unroll
        for (int n = 0; n < 8; ++n) {
            const int col = wc*128 + n*16 + (lane & 15);
            const float bv = b2[col];
#pragma unroll
            for (int r = 0; r < 4; ++r) {
                const int row = m0 + wr*32 + m*16 + ((lane>>4) << 2) + r;
                out[(size_t)row * 256 + col] = fmaxf(acc2[m][n][r] + bv, 0.0f);
            }
        }
    }
}

extern "C" void kernel_launch(void* const* d_in, const int* in_sizes, int n_in,
                              void* d_out, int out_size, void* d_ws, size_t ws_size,
                              hipStream_t stream)
{
    const float* x        = (const float*)d_in[0];
    const float* pos      = (const float*)d_in[1];
    const float* x_skip   = (const float*)d_in[2];
    const float* pos_skip = (const float*)d_in[3];
    const float* W1       = (const float*)d_in[4];
    const float* b1       = (const float*)d_in[5];
    const float* W2       = (const float*)d_in[6];
    const float* b2       = (const float*)d_in[7];
    const int*   batch_skip = (const int*)d_in[9];
    float* out = (float*)d_out;

    char* ws = (char*)d_ws;
    f16*   W1bT = (f16*)ws;                                  // 64 KB
    f16*   W2T  = (f16*)(ws + (256u << 10));                 // 128 KB
    float* b1p  = (float*)(ws + (512u << 10));               // 1 KB
    f16*   y    = (f16*)(ws + (1u << 20));                   // 8 MB

    // gemm_y + wconv + tail
    misc_kernel<<<1665, 256, 0, stream>>>(
        x, pos_skip, batch_skip, W1, W2, b1,
        W1bT, W2T, b1p, y, out + (size_t)MTOT * CHID);

    // in-block kNN + layer1b + gather + layer2
    fused_all<<<MTOT / 64, 256, 0, stream>>>(
        pos, pos_skip, x_skip, W1bT, y, b1p, W2T, b2, out);
}